// Round 1
// baseline (101.513 us; speedup 1.0000x reference)
//
#include <hip/hip_runtime.h>

#define N_GRAPHS 1024
#define D 128
#define EPS 1e-5f

// ---------------------------------------------------------------------------
// Kernel 1: segment boundaries from sorted batch array.
// seg_start[g] = first index i with batch[i] >= g, for g in [0, N_GRAPHS].
// Detects int64 vs int32 storage at runtime: reading the last int32 word of
// the buffer gives the max batch value (~1023, nonzero) if int32 layout, or
// the high word of an int64 element (0) if int64 layout.
// ---------------------------------------------------------------------------
__global__ void seg_bounds_kernel(const int* __restrict__ batch, int n,
                                  int* __restrict__ seg_start) {
    const int probe = batch[n - 1];
    const int is64 = (probe == 0) ? 1 : 0;

    int i = blockIdx.x * blockDim.x + threadIdx.x;
    const int stride = gridDim.x * blockDim.x;
    for (; i < n; i += stride) {
        const int b = is64 ? batch[2 * i] : batch[i];
        const int prev = (i == 0) ? -1 : (is64 ? batch[2 * (i - 1)] : batch[i - 1]);
        for (int g = prev + 1; g <= b; ++g) seg_start[g] = i;
        if (i == n - 1) {
            for (int g = b + 1; g <= N_GRAPHS; ++g) seg_start[g] = n;
        }
    }
}

// ---------------------------------------------------------------------------
// Kernel 2: one block per graph. 256 threads = 32 float4-columns x 8 rowgroups.
// Streams the graph's contiguous node range (coalesced: each wave reads 1KB
// contiguous), reduces across rowgroups in LDS, then wave-0 lanes 0..31 do
// the D=128 LayerNorm via shfl reductions and write out.
// ---------------------------------------------------------------------------
__global__ __launch_bounds__(256)
void readout_kernel(const float4* __restrict__ x4,
                    const int* __restrict__ seg_start,
                    const float* __restrict__ gamma,
                    const float* __restrict__ beta,
                    float4* __restrict__ out) {
    const int g  = blockIdx.x;
    const int t  = threadIdx.x;
    const int q  = t & 31;   // which float4 within the 128-float row
    const int rg = t >> 5;   // row group 0..7

    const int s = seg_start[g];
    const int e = seg_start[g + 1];

    float4 acc = make_float4(0.f, 0.f, 0.f, 0.f);
    for (int i = s + rg; i < e; i += 8) {
        const float4 v = x4[(size_t)i * 32 + q];
        acc.x += v.x; acc.y += v.y; acc.z += v.z; acc.w += v.w;
    }

    __shared__ float4 sh[8][32];
    sh[rg][q] = acc;
    __syncthreads();

    if (rg == 0) {
        float4 tot = sh[0][q];
        #pragma unroll
        for (int k = 1; k < 8; ++k) {
            const float4 v = sh[k][q];
            tot.x += v.x; tot.y += v.y; tot.z += v.z; tot.w += v.w;
        }
        const float cnt = (float)(e - s);
        const float inv = 1.0f / fmaxf(cnt, 1.0f);
        float4 m;
        m.x = tot.x * inv; m.y = tot.y * inv; m.z = tot.z * inv; m.w = tot.w * inv;

        // mean over 128 features (32 lanes x 4)
        float s1 = m.x + m.y + m.z + m.w;
        #pragma unroll
        for (int mask = 16; mask > 0; mask >>= 1) s1 += __shfl_xor(s1, mask);
        const float mu = s1 * (1.0f / 128.0f);

        // biased variance, two-pass for accuracy
        const float dx = m.x - mu, dy = m.y - mu, dz = m.z - mu, dw = m.w - mu;
        float s2 = dx * dx + dy * dy + dz * dz + dw * dw;
        #pragma unroll
        for (int mask = 16; mask > 0; mask >>= 1) s2 += __shfl_xor(s2, mask);
        const float rstd = rsqrtf(s2 * (1.0f / 128.0f) + EPS);

        const float4 gm = ((const float4*)gamma)[q];
        const float4 bt = ((const float4*)beta)[q];
        float4 o;
        o.x = dx * rstd * gm.x + bt.x;
        o.y = dy * rstd * gm.y + bt.y;
        o.z = dz * rstd * gm.z + bt.z;
        o.w = dw * rstd * gm.w + bt.w;
        out[g * 32 + q] = o;
    }
}

extern "C" void kernel_launch(void* const* d_in, const int* in_sizes, int n_in,
                              void* d_out, int out_size, void* d_ws, size_t ws_size,
                              hipStream_t stream) {
    const float* x     = (const float*)d_in[0];
    const int*   batch = (const int*)d_in[1];
    const float* gamma = (const float*)d_in[2];
    const float* beta  = (const float*)d_in[3];
    float*       out   = (float*)d_out;

    const int n_nodes = in_sizes[0] / D;   // 1,000,000
    int* seg_start = (int*)d_ws;           // N_GRAPHS + 1 ints

    seg_bounds_kernel<<<1024, 256, 0, stream>>>(batch, n_nodes, seg_start);
    readout_kernel<<<N_GRAPHS, 256, 0, stream>>>(
        (const float4*)x, seg_start, gamma, beta, (float4*)out);
}

// Round 2
// 99.620 us; speedup vs baseline: 1.0190x; 1.0190x over previous
//
#include <hip/hip_runtime.h>

#define N_GRAPHS 1024
#define D 128
#define EPS 1e-5f

// ---------------------------------------------------------------------------
// Kernel 1: segment boundaries from sorted batch array.
// seg_start[g] = first index i with batch[i] >= g, for g in [0, N_GRAPHS].
// Runtime int64/int32 detection: last int32 word of the buffer is the max
// batch value (~1023, nonzero) for int32 layout, or the zero high word of an
// int64 element for int64 layout.
// ---------------------------------------------------------------------------
__global__ void seg_bounds_kernel(const int* __restrict__ batch, int n,
                                  int* __restrict__ seg_start) {
    const int probe = batch[n - 1];
    const int is64 = (probe == 0) ? 1 : 0;

    int i = blockIdx.x * blockDim.x + threadIdx.x;
    const int stride = gridDim.x * blockDim.x;
    for (; i < n; i += stride) {
        const int b = is64 ? batch[2 * i] : batch[i];
        const int prev = (i == 0) ? -1 : (is64 ? batch[2 * (i - 1)] : batch[i - 1]);
        for (int g = prev + 1; g <= b; ++g) seg_start[g] = i;
        if (i == n - 1) {
            for (int g = b + 1; g <= N_GRAPHS; ++g) seg_start[g] = n;
        }
    }
}

// ---------------------------------------------------------------------------
// Kernel 2: one block per graph. 512 threads = 32 float4-columns x 16
// rowgroups -> 8 waves/block, 4 blocks/CU = 32 waves/CU for latency hiding.
// Streaming loop is 2-deep unrolled (dual accumulators) so each thread keeps
// 2 16B loads in flight. LDS 16x32 float4 reduce, then lanes 0..31 of wave 0
// do the D=128 LayerNorm via shfl reductions.
// ---------------------------------------------------------------------------
__global__ __launch_bounds__(512, 8)
void readout_kernel(const float4* __restrict__ x4,
                    const int* __restrict__ seg_start,
                    const float* __restrict__ gamma,
                    const float* __restrict__ beta,
                    float4* __restrict__ out) {
    const int g  = blockIdx.x;
    const int t  = threadIdx.x;
    const int q  = t & 31;   // float4 column within the 128-float row
    const int rg = t >> 5;   // row group 0..15

    const int s = seg_start[g];
    const int e = seg_start[g + 1];

    float4 a0 = make_float4(0.f, 0.f, 0.f, 0.f);
    float4 a1 = make_float4(0.f, 0.f, 0.f, 0.f);

    const float4* p = x4 + (size_t)(s + rg) * 32 + q;
    int i = s + rg;
    for (; i + 16 < e; i += 32) {
        const float4 v0 = p[0];
        const float4 v1 = p[16 * 32];
        p += 32 * 32;
        a0.x += v0.x; a0.y += v0.y; a0.z += v0.z; a0.w += v0.w;
        a1.x += v1.x; a1.y += v1.y; a1.z += v1.z; a1.w += v1.w;
    }
    if (i < e) {
        const float4 v0 = p[0];
        a0.x += v0.x; a0.y += v0.y; a0.z += v0.z; a0.w += v0.w;
    }
    a0.x += a1.x; a0.y += a1.y; a0.z += a1.z; a0.w += a1.w;

    __shared__ float4 sh[16][32];
    sh[rg][q] = a0;
    __syncthreads();

    if (rg == 0) {
        float4 tot = sh[0][q];
        #pragma unroll
        for (int k = 1; k < 16; ++k) {
            const float4 v = sh[k][q];
            tot.x += v.x; tot.y += v.y; tot.z += v.z; tot.w += v.w;
        }
        const float cnt = (float)(e - s);
        const float inv = 1.0f / fmaxf(cnt, 1.0f);
        float4 m;
        m.x = tot.x * inv; m.y = tot.y * inv; m.z = tot.z * inv; m.w = tot.w * inv;

        // mean over 128 features (32 lanes x 4)
        float s1 = m.x + m.y + m.z + m.w;
        #pragma unroll
        for (int mask = 16; mask > 0; mask >>= 1) s1 += __shfl_xor(s1, mask);
        const float mu = s1 * (1.0f / 128.0f);

        // biased variance, two-pass for accuracy
        const float dx = m.x - mu, dy = m.y - mu, dz = m.z - mu, dw = m.w - mu;
        float s2 = dx * dx + dy * dy + dz * dz + dw * dw;
        #pragma unroll
        for (int mask = 16; mask > 0; mask >>= 1) s2 += __shfl_xor(s2, mask);
        const float rstd = rsqrtf(s2 * (1.0f / 128.0f) + EPS);

        const float4 gm = ((const float4*)gamma)[q];
        const float4 bt = ((const float4*)beta)[q];
        float4 o;
        o.x = dx * rstd * gm.x + bt.x;
        o.y = dy * rstd * gm.y + bt.y;
        o.z = dz * rstd * gm.z + bt.z;
        o.w = dw * rstd * gm.w + bt.w;
        out[g * 32 + q] = o;
    }
}

extern "C" void kernel_launch(void* const* d_in, const int* in_sizes, int n_in,
                              void* d_out, int out_size, void* d_ws, size_t ws_size,
                              hipStream_t stream) {
    const float* x     = (const float*)d_in[0];
    const int*   batch = (const int*)d_in[1];
    const float* gamma = (const float*)d_in[2];
    const float* beta  = (const float*)d_in[3];
    float*       out   = (float*)d_out;

    const int n_nodes = in_sizes[0] / D;   // 1,000,000
    int* seg_start = (int*)d_ws;           // N_GRAPHS + 1 ints

    seg_bounds_kernel<<<1024, 256, 0, stream>>>(batch, n_nodes, seg_start);
    readout_kernel<<<N_GRAPHS, 512, 0, stream>>>(
        (const float4*)x, seg_start, gamma, beta, (float4*)out);
}

// Round 3
// 87.500 us; speedup vs baseline: 1.1602x; 1.1385x over previous
//
#include <hip/hip_runtime.h>

#define N_GRAPHS 1024
#define D 128
#define EPS 1e-5f

typedef float f4 __attribute__((ext_vector_type(4)));

// ---------------------------------------------------------------------------
// Kernel 1: segment boundaries from sorted batch array.
// seg_start[g] = first index i with batch[i] >= g, for g in [0, N_GRAPHS].
// Runtime int64/int32 detection: last int32 word of the buffer is the max
// batch value (~1023, nonzero) for int32 layout, or the zero high word of an
// int64 element for int64 layout.
// ---------------------------------------------------------------------------
__global__ void seg_bounds_kernel(const int* __restrict__ batch, int n,
                                  int* __restrict__ seg_start) {
    const int probe = batch[n - 1];
    const int is64 = (probe == 0) ? 1 : 0;

    int i = blockIdx.x * blockDim.x + threadIdx.x;
    const int stride = gridDim.x * blockDim.x;
    for (; i < n; i += stride) {
        const int b = __builtin_nontemporal_load(batch + (is64 ? 2 * i : i));
        const int prev = (i == 0) ? -1
            : __builtin_nontemporal_load(batch + (is64 ? 2 * (i - 1) : (i - 1)));
        for (int g = prev + 1; g <= b; ++g) seg_start[g] = i;
        if (i == n - 1) {
            for (int g = b + 1; g <= N_GRAPHS; ++g) seg_start[g] = n;
        }
    }
}

// ---------------------------------------------------------------------------
// Kernel 2: one block per graph. 512 threads = 32 float4-columns x 16
// rowgroups (8 waves/block, 4 blocks/CU = 32 waves/CU). Streaming loop is
// 2-deep unrolled with NONTEMPORAL loads (x is read exactly once -> bypass
// L2 allocation). LDS 16x32 f4 reduce, then lanes 0..31 of wave 0 do the
// D=128 LayerNorm via shfl reductions.
// ---------------------------------------------------------------------------
__global__ __launch_bounds__(512, 8)
void readout_kernel(const f4* __restrict__ x4,
                    const int* __restrict__ seg_start,
                    const float* __restrict__ gamma,
                    const float* __restrict__ beta,
                    f4* __restrict__ out) {
    const int g  = blockIdx.x;
    const int t  = threadIdx.x;
    const int q  = t & 31;   // f4 column within the 128-float row
    const int rg = t >> 5;   // row group 0..15

    const int s = seg_start[g];
    const int e = seg_start[g + 1];

    f4 a0 = (f4)(0.f);
    f4 a1 = (f4)(0.f);

    const f4* p = x4 + (size_t)(s + rg) * 32 + q;
    int i = s + rg;
    for (; i + 16 < e; i += 32) {
        const f4 v0 = __builtin_nontemporal_load(&p[0]);
        const f4 v1 = __builtin_nontemporal_load(&p[16 * 32]);
        p += 32 * 32;
        a0 += v0;
        a1 += v1;
    }
    if (i < e) {
        a0 += __builtin_nontemporal_load(&p[0]);
    }
    a0 += a1;

    __shared__ f4 sh[16][32];
    sh[rg][q] = a0;
    __syncthreads();

    if (rg == 0) {
        f4 tot = sh[0][q];
        #pragma unroll
        for (int k = 1; k < 16; ++k) tot += sh[k][q];

        const float cnt = (float)(e - s);
        const float inv = 1.0f / fmaxf(cnt, 1.0f);
        const f4 m = tot * inv;

        // mean over 128 features (32 lanes x 4)
        float s1 = m.x + m.y + m.z + m.w;
        #pragma unroll
        for (int mask = 16; mask > 0; mask >>= 1) s1 += __shfl_xor(s1, mask);
        const float mu = s1 * (1.0f / 128.0f);

        // biased variance, two-pass for accuracy
        const f4 d = m - mu;
        float s2 = d.x * d.x + d.y * d.y + d.z * d.z + d.w * d.w;
        #pragma unroll
        for (int mask = 16; mask > 0; mask >>= 1) s2 += __shfl_xor(s2, mask);
        const float rstd = rsqrtf(s2 * (1.0f / 128.0f) + EPS);

        const f4 gm = *(const f4*)(gamma + 4 * q);
        const f4 bt = *(const f4*)(beta + 4 * q);
        const f4 o = d * rstd * gm + bt;
        out[g * 32 + q] = o;
    }
}

extern "C" void kernel_launch(void* const* d_in, const int* in_sizes, int n_in,
                              void* d_out, int out_size, void* d_ws, size_t ws_size,
                              hipStream_t stream) {
    const float* x     = (const float*)d_in[0];
    const int*   batch = (const int*)d_in[1];
    const float* gamma = (const float*)d_in[2];
    const float* beta  = (const float*)d_in[3];
    f4*          out   = (f4*)d_out;

    const int n_nodes = in_sizes[0] / D;   // 1,000,000
    int* seg_start = (int*)d_ws;           // N_GRAPHS + 1 ints

    seg_bounds_kernel<<<1024, 256, 0, stream>>>(batch, n_nodes, seg_start);
    readout_kernel<<<N_GRAPHS, 512, 0, stream>>>(
        (const f4*)x, seg_start, gamma, beta, out);
}

// Round 4
// 84.737 us; speedup vs baseline: 1.1980x; 1.0326x over previous
//
#include <hip/hip_runtime.h>

#define N_GRAPHS 1024
#define D 128
#define EPS 1e-5f

typedef float f4 __attribute__((ext_vector_type(4)));

// ---------------------------------------------------------------------------
// Single fused kernel. One block per graph, 512 threads = 32 f4-columns x 16
// rowgroups (8 waves/block, 4 blocks/CU = 32 waves/CU).
//
// Phase 1 (wave 0 only): wave-parallel 32-ary lower_bound on the sorted batch
// array. Lanes 0-31 find s = lb(g), lanes 32-63 find e = lb(g+1). Each step
// probes 32 split points of [lo,hi] and uses __ballot to find the predicate
// crossing -> range shrinks ~32x per step, 4-5 steps for n=1e6. Probes are
// shared across blocks (same midpoints early on) -> L2-hit.
// Runtime int64/int32 detection: last int32 word is the (nonzero) max batch
// value for int32 layout, or the zero high word of an int64 element.
//
// Phase 2: stream rows [s,e) with nontemporal f4 loads (read-once -> bypass
// L2), 2-deep unrolled dual accumulators. LDS 16x32 reduce, then lanes 0..31
// of wave 0 do the D=128 LayerNorm via shfl and write 512B.
// ---------------------------------------------------------------------------
__global__ __launch_bounds__(512, 8)
void fused_readout_kernel(const f4* __restrict__ x4,
                          const int* __restrict__ batch32,
                          int n,
                          const float* __restrict__ gamma,
                          const float* __restrict__ beta,
                          f4* __restrict__ out) {
    const int g  = blockIdx.x;
    const int t  = threadIdx.x;
    const int q  = t & 31;   // f4 column within the 128-float row
    const int rg = t >> 5;   // row group 0..15

    __shared__ int bounds[2];

    if (t < 64) {
        const int l = t & 31;            // lane within 32-group
        const int v = g + (t >> 5);      // lanes 0-31: g, lanes 32-63: g+1
        const int is64 = (batch32[n - 1] == 0) ? 1 : 0;
        // invariant: pred(lo)=false, pred(hi)=true, pred(i) := batch[i] >= v
        // (virtual batch[-1] = -inf, batch[n] = +inf); answer = hi at gap==1.
        int lo = -1, hi = n;
        while (hi - lo > 1) {
            const int gap = hi - lo;
            const int pos = lo + 1 + (int)(((long long)(gap - 1) * l) >> 5);
            const int bv = batch32[is64 ? (pos << 1) : pos];
            const unsigned long long m = __ballot(bv >= v);
            const unsigned int gm = (unsigned int)(m >> (t & 32));
            if (gm == 0) {
                // all probes false: largest probe (j=31) becomes new lo
                lo = lo + 1 + (int)(((long long)(gap - 1) * 31) >> 5);
            } else {
                const int j = __builtin_ctz(gm);
                hi = lo + 1 + (int)(((long long)(gap - 1) * j) >> 5);
                if (j > 0)
                    lo = lo + 1 + (int)(((long long)(gap - 1) * (j - 1)) >> 5);
            }
        }
        if (l == 0) bounds[t >> 5] = hi;
    }
    __syncthreads();

    const int s = bounds[0];
    const int e = bounds[1];

    f4 a0 = (f4)(0.f);
    f4 a1 = (f4)(0.f);

    const f4* p = x4 + (size_t)(s + rg) * 32 + q;
    int i = s + rg;
    for (; i + 16 < e; i += 32) {
        const f4 v0 = __builtin_nontemporal_load(&p[0]);
        const f4 v1 = __builtin_nontemporal_load(&p[16 * 32]);
        p += 32 * 32;
        a0 += v0;
        a1 += v1;
    }
    if (i < e) {
        a0 += __builtin_nontemporal_load(&p[0]);
    }
    a0 += a1;

    __shared__ f4 sh[16][32];
    sh[rg][q] = a0;
    __syncthreads();

    if (rg == 0) {
        f4 tot = sh[0][q];
        #pragma unroll
        for (int k = 1; k < 16; ++k) tot += sh[k][q];

        const float cnt = (float)(e - s);
        const float inv = 1.0f / fmaxf(cnt, 1.0f);
        const f4 m = tot * inv;

        // mean over 128 features (32 lanes x 4)
        float s1 = m.x + m.y + m.z + m.w;
        #pragma unroll
        for (int mask = 16; mask > 0; mask >>= 1) s1 += __shfl_xor(s1, mask);
        const float mu = s1 * (1.0f / 128.0f);

        // biased variance, two-pass
        const f4 d = m - mu;
        float s2 = d.x * d.x + d.y * d.y + d.z * d.z + d.w * d.w;
        #pragma unroll
        for (int mask = 16; mask > 0; mask >>= 1) s2 += __shfl_xor(s2, mask);
        const float rstd = rsqrtf(s2 * (1.0f / 128.0f) + EPS);

        const f4 gm = *(const f4*)(gamma + 4 * q);
        const f4 bt = *(const f4*)(beta + 4 * q);
        const f4 o = d * rstd * gm + bt;
        out[g * 32 + q] = o;
    }
}

extern "C" void kernel_launch(void* const* d_in, const int* in_sizes, int n_in,
                              void* d_out, int out_size, void* d_ws, size_t ws_size,
                              hipStream_t stream) {
    const float* x     = (const float*)d_in[0];
    const int*   batch = (const int*)d_in[1];
    const float* gamma = (const float*)d_in[2];
    const float* beta  = (const float*)d_in[3];
    f4*          out   = (f4*)d_out;

    const int n_nodes = in_sizes[0] / D;   // 1,000,000

    fused_readout_kernel<<<N_GRAPHS, 512, 0, stream>>>(
        (const f4*)x, batch, n_nodes, gamma, beta, out);
}